// Round 3
// baseline (3164.631 us; speedup 1.0000x reference)
//
#include <hip/hip_runtime.h>
#include <math.h>

#define N_ROWS 32768
#define DIM 256
#define K_CODES 1024

// ---- workspace float offsets (total ~1.2 MB) ----
#define WS_LOSS   0        // 1024 distributed loss slots
#define WS_NSUM   1024
#define WS_ZZ     2048     // 32768
#define WS_EE     34816    // 1024
#define WS_COUNTS 35840    // 1024
#define WS_ESUM   36864    // 1024*256
#define WS_TOTAL  (36864 + K_CODES * DIM)   // 299008 floats

// ---- output float offsets (return-order concatenation) ----
#define OFF_ZQ    0ull
#define OFF_CODES 8388608ull
#define OFF_LOSS  8421376ull
#define OFF_PERP  8421377ull
#define OFF_ENT   8421378ull
#define OFF_SOFT  8421379ull          // %4==3 -> scalar access in this region
#define OFF_NEMB  41975811ull
#define OFF_NCS   42237955ull
#define OFF_NEA   42238979ull

__global__ __launch_bounds__(256) void k0_zero(float* ws) {
    int i = blockIdx.x * 256 + threadIdx.x;
    if (i < WS_TOTAL) ws[i] = 0.0f;
}

// one wave per row: zz[n]=||z_n||^2 for rows < N_ROWS, ee[k]=||e_k||^2 otherwise
__global__ __launch_bounds__(256) void k1_norms(const float* __restrict__ z,
                                                const float* __restrict__ embed,
                                                float* __restrict__ ws) {
    int wave = threadIdx.x >> 6;
    int lane = threadIdx.x & 63;
    int row = blockIdx.x * 4 + wave;
    const float* src = (row < N_ROWS) ? (z + (size_t)row * DIM)
                                      : (embed + (size_t)(row - N_ROWS) * DIM);
    float4 v = *(const float4*)(src + lane * 4);
    float s = v.x * v.x + v.y * v.y + v.z * v.z + v.w * v.w;
    #pragma unroll
    for (int off = 32; off; off >>= 1) s += __shfl_down(s, off, 64);
    if (lane == 0) {
        if (row < N_ROWS) ws[WS_ZZ + row] = s;
        else              ws[WS_EE + (row - N_ROWS)] = s;
    }
}

// Fused dist-GEMM + argmin + softmax + z_q + loss + EMA scatter.
// R3 vs R2: double-buffered LDS + register prefetch (T14 async-split).
// Per phase: issue global loads for t+1 -> compute t from LDS -> ds_write t+1
// into the other buffer -> ONE __syncthreads. Global-load latency hides under
// ~2048 cycles of FMA issue; barrier count halves. __launch_bounds__(512,4)
// caps VGPR at 128 so 2 blocks/CU stay resident (139 KB LDS).
// FMA order (d = 0..255 sequential) and (zz - 2*acc) + ee unchanged ->
// dist values bit-identical to the verified R2 kernel.
__global__ __launch_bounds__(512, 4) void k23_fused(const float* __restrict__ z,
                                                    const float* __restrict__ embed,
                                                    float* __restrict__ ws,
                                                    float* __restrict__ out) {
    __shared__ float sB[2][8][1024];   // embed^T tiles: sB[buf][d][code]  (64 KB)
    __shared__ float sA[2][8][32];     // z^T tiles: sA[buf][d][row]
    __shared__ float red [4][8][2];    // [rg][i][wave-in-pair] reduce scratch
    __shared__ int   redi[4][8][2];
    __shared__ float rowmin[32];
    __shared__ int   rowcode[32];
    __shared__ float rowsum[32];
    __shared__ int   rownc[32];
    __shared__ int   rowcand[32][8];
    __shared__ double sdd[8];
    __shared__ int   anytie;

    int tid  = threadIdx.x;
    int lane = tid & 63;
    int wid  = tid >> 6;          // 0..7
    int rg   = tid >> 7;          // 0..3
    int c    = tid & 127;         // 0..127
    int wid2 = wid & 1;           // which wave of the 2-wave rowgroup
    int rowBase = blockIdx.x * 32;
    int base_r  = rg * 8;

    // per-thread staging assignment (fixed across phases)
    int sg_code[4], sg_chunk[4];
    #pragma unroll
    for (int it = 0; it < 4; ++it) {
        int g = it * 512 + tid;              // 0..2047
        sg_code[it] = g >> 1; sg_chunk[it] = g & 1;
    }
    int sa_row = tid >> 1, sa_chunk = tid & 1;   // valid when tid < 64

    float acc[8][8];
    #pragma unroll
    for (int i = 0; i < 8; ++i)
        #pragma unroll
        for (int j = 0; j < 8; ++j) acc[i][j] = 0.f;

    float4 pb0, pb1, pb2, pb3, pa;

    // ---- prologue: stage phase 0 into buf 0 ----
    {
        int d0 = 0;
        pb0 = *(const float4*)&embed[(size_t)sg_code[0] * DIM + d0 + sg_chunk[0] * 4];
        pb1 = *(const float4*)&embed[(size_t)sg_code[1] * DIM + d0 + sg_chunk[1] * 4];
        pb2 = *(const float4*)&embed[(size_t)sg_code[2] * DIM + d0 + sg_chunk[2] * 4];
        pb3 = *(const float4*)&embed[(size_t)sg_code[3] * DIM + d0 + sg_chunk[3] * 4];
        if (tid < 64)
            pa = *(const float4*)&z[(size_t)(rowBase + sa_row) * DIM + d0 + sa_chunk * 4];
        sB[0][sg_chunk[0]*4+0][sg_code[0]] = pb0.x; sB[0][sg_chunk[0]*4+1][sg_code[0]] = pb0.y;
        sB[0][sg_chunk[0]*4+2][sg_code[0]] = pb0.z; sB[0][sg_chunk[0]*4+3][sg_code[0]] = pb0.w;
        sB[0][sg_chunk[1]*4+0][sg_code[1]] = pb1.x; sB[0][sg_chunk[1]*4+1][sg_code[1]] = pb1.y;
        sB[0][sg_chunk[1]*4+2][sg_code[1]] = pb1.z; sB[0][sg_chunk[1]*4+3][sg_code[1]] = pb1.w;
        sB[0][sg_chunk[2]*4+0][sg_code[2]] = pb2.x; sB[0][sg_chunk[2]*4+1][sg_code[2]] = pb2.y;
        sB[0][sg_chunk[2]*4+2][sg_code[2]] = pb2.z; sB[0][sg_chunk[2]*4+3][sg_code[2]] = pb2.w;
        sB[0][sg_chunk[3]*4+0][sg_code[3]] = pb3.x; sB[0][sg_chunk[3]*4+1][sg_code[3]] = pb3.y;
        sB[0][sg_chunk[3]*4+2][sg_code[3]] = pb3.z; sB[0][sg_chunk[3]*4+3][sg_code[3]] = pb3.w;
        if (tid < 64) {
            sA[0][sa_chunk*4+0][sa_row] = pa.x; sA[0][sa_chunk*4+1][sa_row] = pa.y;
            sA[0][sa_chunk*4+2][sa_row] = pa.z; sA[0][sa_chunk*4+3][sa_row] = pa.w;
        }
    }
    __syncthreads();

    // ---- main pipeline: 31 iterations of {prefetch t+1, compute t, write t+1} ----
    int cur = 0;
    for (int dt = 0; dt < 31; ++dt) {
        int d0n = (dt + 1) * 8;
        // issue prefetch (latency hides under compute below)
        pb0 = *(const float4*)&embed[(size_t)sg_code[0] * DIM + d0n + sg_chunk[0] * 4];
        pb1 = *(const float4*)&embed[(size_t)sg_code[1] * DIM + d0n + sg_chunk[1] * 4];
        pb2 = *(const float4*)&embed[(size_t)sg_code[2] * DIM + d0n + sg_chunk[2] * 4];
        pb3 = *(const float4*)&embed[(size_t)sg_code[3] * DIM + d0n + sg_chunk[3] * 4];
        if (tid < 64)
            pa = *(const float4*)&z[(size_t)(rowBase + sa_row) * DIM + d0n + sa_chunk * 4];

        // compute current buffer
        #pragma unroll
        for (int d = 0; d < 8; ++d) {
            float4 a0 = *(const float4*)&sA[cur][d][rg * 8];       // wave-uniform broadcast
            float4 a1 = *(const float4*)&sA[cur][d][rg * 8 + 4];
            float av[8] = {a0.x, a0.y, a0.z, a0.w, a1.x, a1.y, a1.z, a1.w};
            float bv[8];
            #pragma unroll
            for (int j = 0; j < 8; ++j) bv[j] = sB[cur][d][c + 128 * j];  // 2-way alias: free
            #pragma unroll
            for (int i = 0; i < 8; ++i)
                #pragma unroll
                for (int j = 0; j < 8; ++j) acc[i][j] += av[i] * bv[j];
        }

        // write prefetched tile into the other buffer (no conflict with readers of cur)
        int nb = cur ^ 1;
        sB[nb][sg_chunk[0]*4+0][sg_code[0]] = pb0.x; sB[nb][sg_chunk[0]*4+1][sg_code[0]] = pb0.y;
        sB[nb][sg_chunk[0]*4+2][sg_code[0]] = pb0.z; sB[nb][sg_chunk[0]*4+3][sg_code[0]] = pb0.w;
        sB[nb][sg_chunk[1]*4+0][sg_code[1]] = pb1.x; sB[nb][sg_chunk[1]*4+1][sg_code[1]] = pb1.y;
        sB[nb][sg_chunk[1]*4+2][sg_code[1]] = pb1.z; sB[nb][sg_chunk[1]*4+3][sg_code[1]] = pb1.w;
        sB[nb][sg_chunk[2]*4+0][sg_code[2]] = pb2.x; sB[nb][sg_chunk[2]*4+1][sg_code[2]] = pb2.y;
        sB[nb][sg_chunk[2]*4+2][sg_code[2]] = pb2.z; sB[nb][sg_chunk[2]*4+3][sg_code[2]] = pb2.w;
        sB[nb][sg_chunk[3]*4+0][sg_code[3]] = pb3.x; sB[nb][sg_chunk[3]*4+1][sg_code[3]] = pb3.y;
        sB[nb][sg_chunk[3]*4+2][sg_code[3]] = pb3.z; sB[nb][sg_chunk[3]*4+3][sg_code[3]] = pb3.w;
        if (tid < 64) {
            sA[nb][sa_chunk*4+0][sa_row] = pa.x; sA[nb][sa_chunk*4+1][sa_row] = pa.y;
            sA[nb][sa_chunk*4+2][sa_row] = pa.z; sA[nb][sa_chunk*4+3][sa_row] = pa.w;
        }
        __syncthreads();
        cur ^= 1;
    }
    // final phase compute (dt = 31)
    #pragma unroll
    for (int d = 0; d < 8; ++d) {
        float4 a0 = *(const float4*)&sA[cur][d][rg * 8];
        float4 a1 = *(const float4*)&sA[cur][d][rg * 8 + 4];
        float av[8] = {a0.x, a0.y, a0.z, a0.w, a1.x, a1.y, a1.z, a1.w};
        float bv[8];
        #pragma unroll
        for (int j = 0; j < 8; ++j) bv[j] = sB[cur][d][c + 128 * j];
        #pragma unroll
        for (int i = 0; i < 8; ++i)
            #pragma unroll
            for (int j = 0; j < 8; ++j) acc[i][j] += av[i] * bv[j];
    }

    // ---------------- dist in registers (identical expression to old k2) --------
    float zzv[8], eev[8];
    #pragma unroll
    for (int i = 0; i < 8; ++i) zzv[i] = ws[WS_ZZ + rowBase + base_r + i];
    #pragma unroll
    for (int j = 0; j < 8; ++j) eev[j] = ws[WS_EE + c + 128 * j];
    #pragma unroll
    for (int i = 0; i < 8; ++i)
        #pragma unroll
        for (int j = 0; j < 8; ++j) acc[i][j] = (zzv[i] - 2.0f * acc[i][j]) + eev[j];

    // ---------------- per-row argmin (lowest-k tiebreak) ------------------------
    #pragma unroll
    for (int i = 0; i < 8; ++i) {
        float v = acc[i][0]; int idx = c;        // j ascending => k ascending
        #pragma unroll
        for (int j = 1; j < 8; ++j) {
            if (acc[i][j] < v) { v = acc[i][j]; idx = c + 128 * j; }
        }
        #pragma unroll
        for (int off = 32; off; off >>= 1) {
            float ov = __shfl_down(v, off, 64);
            int   oi = __shfl_down(idx, off, 64);
            if (ov < v || (ov == v && oi < idx)) { v = ov; idx = oi; }
        }
        if (lane == 0) { red[rg][i][wid2] = v; redi[rg][i][wid2] = idx; }
    }
    if (tid == 0) anytie = 0;
    if (tid < 32) rownc[tid] = 0;
    __syncthreads();
    if (tid < 32) {
        float v0 = red[tid >> 3][tid & 7][0]; int i0 = redi[tid >> 3][tid & 7][0];
        float v1 = red[tid >> 3][tid & 7][1]; int i1 = redi[tid >> 3][tid & 7][1];
        if (v1 < v0 || (v1 == v0 && i1 < i0)) { v0 = v1; i0 = i1; }
        rowmin[tid] = v0; rowcode[tid] = i0;
    }
    __syncthreads();

    // ---------------- near-tie candidates (1e-3 band >> fp32 dist error) --------
    #pragma unroll
    for (int i = 0; i < 8; ++i) {
        int r = base_r + i;
        float thr = rowmin[r] + 1e-3f;
        #pragma unroll
        for (int j = 0; j < 8; ++j) {
            if (acc[i][j] <= thr) {
                int slot = atomicAdd(&rownc[r], 1);
                if (slot < 8) rowcand[r][slot] = c + 128 * j;
            }
        }
    }
    __syncthreads();
    if (tid < 32 && rownc[tid] > 1) atomicAdd(&anytie, 1);
    __syncthreads();
    if (anytie) {    // rare path: fp64 re-dot, numpy-style fp32 final rounding
        for (int r = 0; r < 32; ++r) {
            int nc = rownc[r];
            if (nc <= 1) continue;
            int lim = nc < 8 ? nc : 8;
            int n = rowBase + r;
            float zzn = ws[WS_ZZ + n];
            float bestd = 0.f; int bestk = -1;
            for (int ci = 0; ci < lim; ++ci) {
                int kc = rowcand[r][ci];
                double part = 0.0;
                if (tid < 256)
                    part = (double)z[(size_t)n * DIM + tid] * (double)embed[(size_t)kc * DIM + tid];
                #pragma unroll
                for (int off = 32; off; off >>= 1) part += __shfl_down(part, off, 64);
                if (lane == 0) sdd[wid] = part;
                __syncthreads();
                double dot = 0.0;
                for (int w = 0; w < 8; ++w) dot += sdd[w];
                float d32 = (zzn - 2.0f * (float)dot) + ws[WS_EE + kc];
                if (bestk < 0 || d32 < bestd || (d32 == bestd && kc < bestk)) { bestd = d32; bestk = kc; }
                __syncthreads();     // protect sdd reuse
            }
            if (tid == 0) rowcode[r] = bestk;
        }
        __syncthreads();
    }

    // ---------------- softmax (shift by rowmin is exact-invariant) --------------
    #pragma unroll
    for (int i = 0; i < 8; ++i) {
        float m = rowmin[base_r + i];
        float s = 0.f;
        #pragma unroll
        for (int j = 0; j < 8; ++j) {
            acc[i][j] = __expf((m - acc[i][j]) * 10.0f);
            s += acc[i][j];
        }
        #pragma unroll
        for (int off = 32; off; off >>= 1) s += __shfl_down(s, off, 64);
        if (lane == 0) red[rg][i][wid2] = s;
    }
    __syncthreads();
    if (tid < 32) rowsum[tid] = red[tid >> 3][tid & 7][0] + red[tid >> 3][tid & 7][1];
    __syncthreads();
    #pragma unroll
    for (int i = 0; i < 8; ++i) {
        int n = rowBase + base_r + i;
        float inv = 1.0f / rowsum[base_r + i];
        float* orow = out + OFF_SOFT + (size_t)n * K_CODES;
        #pragma unroll
        for (int j = 0; j < 8; ++j) orow[c + 128 * j] = acc[i][j] * inv;  // lane-coalesced
    }

    // ---------------- z_q, commitment loss, EMA scatter -------------------------
    {
        int r   = tid >> 4;          // 0..31
        int seg = tid & 15;          // 16 threads/row, 16 d each
        int n = rowBase + r;
        int code = rowcode[r];
        int dd = seg * 16;
        float lsum = 0.f;
        #pragma unroll
        for (int q = 0; q < 4; ++q) {
            float4 e4 = *(const float4*)&embed[(size_t)code * DIM + dd + q * 4];
            float4 z4 = *(const float4*)&z[(size_t)n * DIM + dd + q * 4];
            *(float4*)&out[OFF_ZQ + (size_t)n * DIM + dd + q * 4] = e4;
            float dx = z4.x - e4.x, dy = z4.y - e4.y, dz_ = z4.z - e4.z, dw = z4.w - e4.w;
            lsum += dx * dx + dy * dy + dz_ * dz_ + dw * dw;
            atomicAdd(&ws[WS_ESUM + (size_t)code * DIM + dd + q * 4 + 0], z4.x);
            atomicAdd(&ws[WS_ESUM + (size_t)code * DIM + dd + q * 4 + 1], z4.y);
            atomicAdd(&ws[WS_ESUM + (size_t)code * DIM + dd + q * 4 + 2], z4.z);
            atomicAdd(&ws[WS_ESUM + (size_t)code * DIM + dd + q * 4 + 3], z4.w);
        }
        #pragma unroll
        for (int off = 8; off; off >>= 1) lsum += __shfl_down(lsum, off, 16);
        if (seg == 0) {
            atomicAdd(&ws[WS_LOSS + (n & 1023)], lsum);   // 1024-way distributed
            atomicAdd(&ws[WS_COUNTS + code], 1.0f);
            out[OFF_CODES + n] = (float)code;
        }
    }
}

__global__ __launch_bounds__(1024) void k4a_stats(const float* __restrict__ cluster_size,
                                                  float* __restrict__ ws,
                                                  float* __restrict__ out) {
    __shared__ float sm[16];
    int k = threadIdx.x;
    int lane = k & 63, wave = k >> 6;
    float cnt = ws[WS_COUNTS + k];
    float ncs = 0.99f * cluster_size[k] + 0.01f * cnt;
    out[OFF_NCS + k] = ncs;

    // nsum
    float v = ncs;
    #pragma unroll
    for (int off = 32; off; off >>= 1) v += __shfl_down(v, off, 64);
    if (lane == 0) sm[wave] = v;
    __syncthreads();
    if (k == 0) {
        float t = 0.f;
        for (int w = 0; w < 16; ++w) t += sm[w];
        ws[WS_NSUM] = t;
    }
    __syncthreads();

    // entropy
    float avg = cnt / (float)N_ROWS;
    v = -avg * logf(avg + 1e-10f);
    #pragma unroll
    for (int off = 32; off; off >>= 1) v += __shfl_down(v, off, 64);
    if (lane == 0) sm[wave] = v;
    __syncthreads();
    if (k == 0) {
        float ent = 0.f;
        for (int w = 0; w < 16; ++w) ent += sm[w];
        out[OFF_ENT]  = ent;
        out[OFF_PERP] = expf(ent);
    }
    __syncthreads();

    // loss: sum the 1024 distributed slots
    v = ws[WS_LOSS + k];
    #pragma unroll
    for (int off = 32; off; off >>= 1) v += __shfl_down(v, off, 64);
    if (lane == 0) sm[wave] = v;
    __syncthreads();
    if (k == 0) {
        float t = 0.f;
        for (int w = 0; w < 16; ++w) t += sm[w];
        out[OFF_LOSS] = t / 8388608.0f;
    }
}

__global__ __launch_bounds__(256) void k4b_embed(const float* __restrict__ embed_avg,
                                                 const float* __restrict__ ws,
                                                 float* __restrict__ out) {
    int k = blockIdx.x, d = threadIdx.x;
    float es  = ws[WS_ESUM + (size_t)k * DIM + d];
    float nea = 0.99f * embed_avg[(size_t)k * DIM + d] + 0.01f * es;
    out[OFF_NEA + (size_t)k * DIM + d] = nea;
    float ncs  = out[OFF_NCS + k];
    float nsum = ws[WS_NSUM];
    float csn  = (ncs + 1e-5f) / (nsum + K_CODES * 1e-5f) * nsum;
    out[OFF_NEMB + (size_t)k * DIM + d] = nea / csn;
}

extern "C" void kernel_launch(void* const* d_in, const int* in_sizes, int n_in,
                              void* d_out, int out_size, void* d_ws, size_t ws_size,
                              hipStream_t stream) {
    const float* z            = (const float*)d_in[0];
    const float* embed        = (const float*)d_in[1];
    const float* cluster_size = (const float*)d_in[2];
    const float* embed_avg    = (const float*)d_in[3];
    float* out = (float*)d_out;
    float* ws  = (float*)d_ws;

    k0_zero<<<(WS_TOTAL + 255) / 256, 256, 0, stream>>>(ws);
    k1_norms<<<(N_ROWS + K_CODES) / 4, 256, 0, stream>>>(z, embed, ws);
    k23_fused<<<N_ROWS / 32, 512, 0, stream>>>(z, embed, ws, out);
    k4a_stats<<<1, 1024, 0, stream>>>(cluster_size, ws, out);
    k4b_embed<<<K_CODES, 256, 0, stream>>>(embed_avg, ws, out);
}

// Round 4
// 830.299 us; speedup vs baseline: 3.8114x; 3.8114x over previous
//
#include <hip/hip_runtime.h>
#include <math.h>

#define N_ROWS 32768
#define DIM 256
#define K_CODES 1024

// ---- workspace float offsets (total ~1.2 MB) ----
#define WS_LOSS   0        // 1024 distributed loss slots
#define WS_NSUM   1024
#define WS_ZZ     2048     // 32768
#define WS_EE     34816    // 1024
#define WS_COUNTS 35840    // 1024
#define WS_ESUM   36864    // 1024*256
#define WS_TOTAL  (36864 + K_CODES * DIM)   // 299008 floats

// ---- output float offsets (return-order concatenation) ----
#define OFF_ZQ    0ull
#define OFF_CODES 8388608ull
#define OFF_LOSS  8421376ull
#define OFF_PERP  8421377ull
#define OFF_ENT   8421378ull
#define OFF_SOFT  8421379ull          // %4==3 -> scalar access in this region
#define OFF_NEMB  41975811ull
#define OFF_NCS   42237955ull
#define OFF_NEA   42238979ull

__global__ __launch_bounds__(256) void k0_zero(float* ws) {
    int i = blockIdx.x * 256 + threadIdx.x;
    if (i < WS_TOTAL) ws[i] = 0.0f;
}

// one wave per row: zz[n]=||z_n||^2 for rows < N_ROWS, ee[k]=||e_k||^2 otherwise
__global__ __launch_bounds__(256) void k1_norms(const float* __restrict__ z,
                                                const float* __restrict__ embed,
                                                float* __restrict__ ws) {
    int wave = threadIdx.x >> 6;
    int lane = threadIdx.x & 63;
    int row = blockIdx.x * 4 + wave;
    const float* src = (row < N_ROWS) ? (z + (size_t)row * DIM)
                                      : (embed + (size_t)(row - N_ROWS) * DIM);
    float4 v = *(const float4*)(src + lane * 4);
    float s = v.x * v.x + v.y * v.y + v.z * v.z + v.w * v.w;
    #pragma unroll
    for (int off = 32; off; off >>= 1) s += __shfl_down(s, off, 64);
    if (lane == 0) {
        if (row < N_ROWS) ws[WS_ZZ + row] = s;
        else              ws[WS_EE + (row - N_ROWS)] = s;
    }
}

// Fused dist-GEMM + argmin + softmax + z_q + loss + EMA scatter.
// R4 = R3 pipeline with the register bound FIXED.
// EMPIRICAL launch_bounds semantics on this toolchain (R2/R3 data): the 2nd
// arg is min BLOCKS per CU (CUDA semantics), not waves/EU:
//   (512,2) -> 2 blk * 8 waves / 4 SIMD = 4 waves/SIMD -> cap 128 (R2: used 100, no spill)
//   (512,4) -> 8 waves/SIMD -> cap 64  (R3: spilled 14 GB of scratch)
// So (512,2) is the no-spill point. Double-buffered LDS + register prefetch:
// per phase {issue global loads t+1, compute t from LDS, ds_write t+1, ONE
// barrier}. Global latency hides under ~512 FMA issue cycles.
// FMA order (d = 0..255 sequential) and (zz - 2*acc) + ee unchanged ->
// dist values bit-identical to the verified R2 kernel.
__global__ __launch_bounds__(512, 2) void k23_fused(const float* __restrict__ z,
                                                    const float* __restrict__ embed,
                                                    float* __restrict__ ws,
                                                    float* __restrict__ out) {
    __shared__ float sB[2][8][1024];   // embed^T tiles: sB[buf][d][code]  (64 KB)
    __shared__ float sA[2][8][32];     // z^T tiles: sA[buf][d][row]
    __shared__ float red [4][8][2];    // [rg][i][wave-in-pair] reduce scratch
    __shared__ int   redi[4][8][2];
    __shared__ float rowmin[32];
    __shared__ int   rowcode[32];
    __shared__ float rowsum[32];
    __shared__ int   rownc[32];
    __shared__ int   rowcand[32][8];
    __shared__ double sdd[8];
    __shared__ int   anytie;

    int tid  = threadIdx.x;
    int lane = tid & 63;
    int wid  = tid >> 6;          // 0..7
    int rg   = tid >> 7;          // 0..3
    int c    = tid & 127;         // 0..127
    int wid2 = wid & 1;           // which wave of the 2-wave rowgroup
    int rowBase = blockIdx.x * 32;
    int base_r  = rg * 8;

    // per-thread staging assignment (fixed across phases)
    int sg_code[4], sg_chunk[4];
    #pragma unroll
    for (int it = 0; it < 4; ++it) {
        int g = it * 512 + tid;              // 0..2047
        sg_code[it] = g >> 1; sg_chunk[it] = g & 1;
    }
    int sa_row = tid >> 1, sa_chunk = tid & 1;   // valid when tid < 64

    float acc[8][8];
    #pragma unroll
    for (int i = 0; i < 8; ++i)
        #pragma unroll
        for (int j = 0; j < 8; ++j) acc[i][j] = 0.f;

    float4 pb0, pb1, pb2, pb3, pa;

    // ---- prologue: stage phase 0 into buf 0 ----
    {
        int d0 = 0;
        pb0 = *(const float4*)&embed[(size_t)sg_code[0] * DIM + d0 + sg_chunk[0] * 4];
        pb1 = *(const float4*)&embed[(size_t)sg_code[1] * DIM + d0 + sg_chunk[1] * 4];
        pb2 = *(const float4*)&embed[(size_t)sg_code[2] * DIM + d0 + sg_chunk[2] * 4];
        pb3 = *(const float4*)&embed[(size_t)sg_code[3] * DIM + d0 + sg_chunk[3] * 4];
        if (tid < 64)
            pa = *(const float4*)&z[(size_t)(rowBase + sa_row) * DIM + d0 + sa_chunk * 4];
        sB[0][sg_chunk[0]*4+0][sg_code[0]] = pb0.x; sB[0][sg_chunk[0]*4+1][sg_code[0]] = pb0.y;
        sB[0][sg_chunk[0]*4+2][sg_code[0]] = pb0.z; sB[0][sg_chunk[0]*4+3][sg_code[0]] = pb0.w;
        sB[0][sg_chunk[1]*4+0][sg_code[1]] = pb1.x; sB[0][sg_chunk[1]*4+1][sg_code[1]] = pb1.y;
        sB[0][sg_chunk[1]*4+2][sg_code[1]] = pb1.z; sB[0][sg_chunk[1]*4+3][sg_code[1]] = pb1.w;
        sB[0][sg_chunk[2]*4+0][sg_code[2]] = pb2.x; sB[0][sg_chunk[2]*4+1][sg_code[2]] = pb2.y;
        sB[0][sg_chunk[2]*4+2][sg_code[2]] = pb2.z; sB[0][sg_chunk[2]*4+3][sg_code[2]] = pb2.w;
        sB[0][sg_chunk[3]*4+0][sg_code[3]] = pb3.x; sB[0][sg_chunk[3]*4+1][sg_code[3]] = pb3.y;
        sB[0][sg_chunk[3]*4+2][sg_code[3]] = pb3.z; sB[0][sg_chunk[3]*4+3][sg_code[3]] = pb3.w;
        if (tid < 64) {
            sA[0][sa_chunk*4+0][sa_row] = pa.x; sA[0][sa_chunk*4+1][sa_row] = pa.y;
            sA[0][sa_chunk*4+2][sa_row] = pa.z; sA[0][sa_chunk*4+3][sa_row] = pa.w;
        }
    }
    __syncthreads();

    // ---- main pipeline: 31 iterations of {prefetch t+1, compute t, write t+1} ----
    int cur = 0;
    for (int dt = 0; dt < 31; ++dt) {
        int d0n = (dt + 1) * 8;
        // issue prefetch (latency hides under compute below)
        pb0 = *(const float4*)&embed[(size_t)sg_code[0] * DIM + d0n + sg_chunk[0] * 4];
        pb1 = *(const float4*)&embed[(size_t)sg_code[1] * DIM + d0n + sg_chunk[1] * 4];
        pb2 = *(const float4*)&embed[(size_t)sg_code[2] * DIM + d0n + sg_chunk[2] * 4];
        pb3 = *(const float4*)&embed[(size_t)sg_code[3] * DIM + d0n + sg_chunk[3] * 4];
        if (tid < 64)
            pa = *(const float4*)&z[(size_t)(rowBase + sa_row) * DIM + d0n + sa_chunk * 4];

        // compute current buffer
        #pragma unroll
        for (int d = 0; d < 8; ++d) {
            float4 a0 = *(const float4*)&sA[cur][d][rg * 8];       // wave-uniform broadcast
            float4 a1 = *(const float4*)&sA[cur][d][rg * 8 + 4];
            float av[8] = {a0.x, a0.y, a0.z, a0.w, a1.x, a1.y, a1.z, a1.w};
            float bv[8];
            #pragma unroll
            for (int j = 0; j < 8; ++j) bv[j] = sB[cur][d][c + 128 * j];  // 2-way alias: free
            #pragma unroll
            for (int i = 0; i < 8; ++i)
                #pragma unroll
                for (int j = 0; j < 8; ++j) acc[i][j] += av[i] * bv[j];
        }

        // write prefetched tile into the other buffer (no conflict with readers of cur)
        int nb = cur ^ 1;
        sB[nb][sg_chunk[0]*4+0][sg_code[0]] = pb0.x; sB[nb][sg_chunk[0]*4+1][sg_code[0]] = pb0.y;
        sB[nb][sg_chunk[0]*4+2][sg_code[0]] = pb0.z; sB[nb][sg_chunk[0]*4+3][sg_code[0]] = pb0.w;
        sB[nb][sg_chunk[1]*4+0][sg_code[1]] = pb1.x; sB[nb][sg_chunk[1]*4+1][sg_code[1]] = pb1.y;
        sB[nb][sg_chunk[1]*4+2][sg_code[1]] = pb1.z; sB[nb][sg_chunk[1]*4+3][sg_code[1]] = pb1.w;
        sB[nb][sg_chunk[2]*4+0][sg_code[2]] = pb2.x; sB[nb][sg_chunk[2]*4+1][sg_code[2]] = pb2.y;
        sB[nb][sg_chunk[2]*4+2][sg_code[2]] = pb2.z; sB[nb][sg_chunk[2]*4+3][sg_code[2]] = pb2.w;
        sB[nb][sg_chunk[3]*4+0][sg_code[3]] = pb3.x; sB[nb][sg_chunk[3]*4+1][sg_code[3]] = pb3.y;
        sB[nb][sg_chunk[3]*4+2][sg_code[3]] = pb3.z; sB[nb][sg_chunk[3]*4+3][sg_code[3]] = pb3.w;
        if (tid < 64) {
            sA[nb][sa_chunk*4+0][sa_row] = pa.x; sA[nb][sa_chunk*4+1][sa_row] = pa.y;
            sA[nb][sa_chunk*4+2][sa_row] = pa.z; sA[nb][sa_chunk*4+3][sa_row] = pa.w;
        }
        __syncthreads();
        cur ^= 1;
    }
    // final phase compute (dt = 31)
    #pragma unroll
    for (int d = 0; d < 8; ++d) {
        float4 a0 = *(const float4*)&sA[cur][d][rg * 8];
        float4 a1 = *(const float4*)&sA[cur][d][rg * 8 + 4];
        float av[8] = {a0.x, a0.y, a0.z, a0.w, a1.x, a1.y, a1.z, a1.w};
        float bv[8];
        #pragma unroll
        for (int j = 0; j < 8; ++j) bv[j] = sB[cur][d][c + 128 * j];
        #pragma unroll
        for (int i = 0; i < 8; ++i)
            #pragma unroll
            for (int j = 0; j < 8; ++j) acc[i][j] += av[i] * bv[j];
    }

    // ---------------- dist in registers (identical expression to old k2) --------
    float zzv[8], eev[8];
    #pragma unroll
    for (int i = 0; i < 8; ++i) zzv[i] = ws[WS_ZZ + rowBase + base_r + i];
    #pragma unroll
    for (int j = 0; j < 8; ++j) eev[j] = ws[WS_EE + c + 128 * j];
    #pragma unroll
    for (int i = 0; i < 8; ++i)
        #pragma unroll
        for (int j = 0; j < 8; ++j) acc[i][j] = (zzv[i] - 2.0f * acc[i][j]) + eev[j];

    // ---------------- per-row argmin (lowest-k tiebreak) ------------------------
    #pragma unroll
    for (int i = 0; i < 8; ++i) {
        float v = acc[i][0]; int idx = c;        // j ascending => k ascending
        #pragma unroll
        for (int j = 1; j < 8; ++j) {
            if (acc[i][j] < v) { v = acc[i][j]; idx = c + 128 * j; }
        }
        #pragma unroll
        for (int off = 32; off; off >>= 1) {
            float ov = __shfl_down(v, off, 64);
            int   oi = __shfl_down(idx, off, 64);
            if (ov < v || (ov == v && oi < idx)) { v = ov; idx = oi; }
        }
        if (lane == 0) { red[rg][i][wid2] = v; redi[rg][i][wid2] = idx; }
    }
    if (tid == 0) anytie = 0;
    if (tid < 32) rownc[tid] = 0;
    __syncthreads();
    if (tid < 32) {
        float v0 = red[tid >> 3][tid & 7][0]; int i0 = redi[tid >> 3][tid & 7][0];
        float v1 = red[tid >> 3][tid & 7][1]; int i1 = redi[tid >> 3][tid & 7][1];
        if (v1 < v0 || (v1 == v0 && i1 < i0)) { v0 = v1; i0 = i1; }
        rowmin[tid] = v0; rowcode[tid] = i0;
    }
    __syncthreads();

    // ---------------- near-tie candidates (1e-3 band >> fp32 dist error) --------
    #pragma unroll
    for (int i = 0; i < 8; ++i) {
        int r = base_r + i;
        float thr = rowmin[r] + 1e-3f;
        #pragma unroll
        for (int j = 0; j < 8; ++j) {
            if (acc[i][j] <= thr) {
                int slot = atomicAdd(&rownc[r], 1);
                if (slot < 8) rowcand[r][slot] = c + 128 * j;
            }
        }
    }
    __syncthreads();
    if (tid < 32 && rownc[tid] > 1) atomicAdd(&anytie, 1);
    __syncthreads();
    if (anytie) {    // rare path: fp64 re-dot, numpy-style fp32 final rounding
        for (int r = 0; r < 32; ++r) {
            int nc = rownc[r];
            if (nc <= 1) continue;
            int lim = nc < 8 ? nc : 8;
            int n = rowBase + r;
            float zzn = ws[WS_ZZ + n];
            float bestd = 0.f; int bestk = -1;
            for (int ci = 0; ci < lim; ++ci) {
                int kc = rowcand[r][ci];
                double part = 0.0;
                if (tid < 256)
                    part = (double)z[(size_t)n * DIM + tid] * (double)embed[(size_t)kc * DIM + tid];
                #pragma unroll
                for (int off = 32; off; off >>= 1) part += __shfl_down(part, off, 64);
                if (lane == 0) sdd[wid] = part;
                __syncthreads();
                double dot = 0.0;
                for (int w = 0; w < 8; ++w) dot += sdd[w];
                float d32 = (zzn - 2.0f * (float)dot) + ws[WS_EE + kc];
                if (bestk < 0 || d32 < bestd || (d32 == bestd && kc < bestk)) { bestd = d32; bestk = kc; }
                __syncthreads();     // protect sdd reuse
            }
            if (tid == 0) rowcode[r] = bestk;
        }
        __syncthreads();
    }

    // ---------------- softmax (shift by rowmin is exact-invariant) --------------
    #pragma unroll
    for (int i = 0; i < 8; ++i) {
        float m = rowmin[base_r + i];
        float s = 0.f;
        #pragma unroll
        for (int j = 0; j < 8; ++j) {
            acc[i][j] = __expf((m - acc[i][j]) * 10.0f);
            s += acc[i][j];
        }
        #pragma unroll
        for (int off = 32; off; off >>= 1) s += __shfl_down(s, off, 64);
        if (lane == 0) red[rg][i][wid2] = s;
    }
    __syncthreads();
    if (tid < 32) rowsum[tid] = red[tid >> 3][tid & 7][0] + red[tid >> 3][tid & 7][1];
    __syncthreads();
    #pragma unroll
    for (int i = 0; i < 8; ++i) {
        int n = rowBase + base_r + i;
        float inv = 1.0f / rowsum[base_r + i];
        float* orow = out + OFF_SOFT + (size_t)n * K_CODES;
        #pragma unroll
        for (int j = 0; j < 8; ++j) orow[c + 128 * j] = acc[i][j] * inv;  // lane-coalesced
    }

    // ---------------- z_q, commitment loss, EMA scatter -------------------------
    {
        int r   = tid >> 4;          // 0..31
        int seg = tid & 15;          // 16 threads/row, 16 d each
        int n = rowBase + r;
        int code = rowcode[r];
        int dd = seg * 16;
        float lsum = 0.f;
        #pragma unroll
        for (int q = 0; q < 4; ++q) {
            float4 e4 = *(const float4*)&embed[(size_t)code * DIM + dd + q * 4];
            float4 z4 = *(const float4*)&z[(size_t)n * DIM + dd + q * 4];
            *(float4*)&out[OFF_ZQ + (size_t)n * DIM + dd + q * 4] = e4;
            float dx = z4.x - e4.x, dy = z4.y - e4.y, dz_ = z4.z - e4.z, dw = z4.w - e4.w;
            lsum += dx * dx + dy * dy + dz_ * dz_ + dw * dw;
            atomicAdd(&ws[WS_ESUM + (size_t)code * DIM + dd + q * 4 + 0], z4.x);
            atomicAdd(&ws[WS_ESUM + (size_t)code * DIM + dd + q * 4 + 1], z4.y);
            atomicAdd(&ws[WS_ESUM + (size_t)code * DIM + dd + q * 4 + 2], z4.z);
            atomicAdd(&ws[WS_ESUM + (size_t)code * DIM + dd + q * 4 + 3], z4.w);
        }
        #pragma unroll
        for (int off = 8; off; off >>= 1) lsum += __shfl_down(lsum, off, 16);
        if (seg == 0) {
            atomicAdd(&ws[WS_LOSS + (n & 1023)], lsum);   // 1024-way distributed
            atomicAdd(&ws[WS_COUNTS + code], 1.0f);
            out[OFF_CODES + n] = (float)code;
        }
    }
}

__global__ __launch_bounds__(1024) void k4a_stats(const float* __restrict__ cluster_size,
                                                  float* __restrict__ ws,
                                                  float* __restrict__ out) {
    __shared__ float sm[16];
    int k = threadIdx.x;
    int lane = k & 63, wave = k >> 6;
    float cnt = ws[WS_COUNTS + k];
    float ncs = 0.99f * cluster_size[k] + 0.01f * cnt;
    out[OFF_NCS + k] = ncs;

    // nsum
    float v = ncs;
    #pragma unroll
    for (int off = 32; off; off >>= 1) v += __shfl_down(v, off, 64);
    if (lane == 0) sm[wave] = v;
    __syncthreads();
    if (k == 0) {
        float t = 0.f;
        for (int w = 0; w < 16; ++w) t += sm[w];
        ws[WS_NSUM] = t;
    }
    __syncthreads();

    // entropy
    float avg = cnt / (float)N_ROWS;
    v = -avg * logf(avg + 1e-10f);
    #pragma unroll
    for (int off = 32; off; off >>= 1) v += __shfl_down(v, off, 64);
    if (lane == 0) sm[wave] = v;
    __syncthreads();
    if (k == 0) {
        float ent = 0.f;
        for (int w = 0; w < 16; ++w) ent += sm[w];
        out[OFF_ENT]  = ent;
        out[OFF_PERP] = expf(ent);
    }
    __syncthreads();

    // loss: sum the 1024 distributed slots
    v = ws[WS_LOSS + k];
    #pragma unroll
    for (int off = 32; off; off >>= 1) v += __shfl_down(v, off, 64);
    if (lane == 0) sm[wave] = v;
    __syncthreads();
    if (k == 0) {
        float t = 0.f;
        for (int w = 0; w < 16; ++w) t += sm[w];
        out[OFF_LOSS] = t / 8388608.0f;
    }
}

__global__ __launch_bounds__(256) void k4b_embed(const float* __restrict__ embed_avg,
                                                 const float* __restrict__ ws,
                                                 float* __restrict__ out) {
    int k = blockIdx.x, d = threadIdx.x;
    float es  = ws[WS_ESUM + (size_t)k * DIM + d];
    float nea = 0.99f * embed_avg[(size_t)k * DIM + d] + 0.01f * es;
    out[OFF_NEA + (size_t)k * DIM + d] = nea;
    float ncs  = out[OFF_NCS + k];
    float nsum = ws[WS_NSUM];
    float csn  = (ncs + 1e-5f) / (nsum + K_CODES * 1e-5f) * nsum;
    out[OFF_NEMB + (size_t)k * DIM + d] = nea / csn;
}

extern "C" void kernel_launch(void* const* d_in, const int* in_sizes, int n_in,
                              void* d_out, int out_size, void* d_ws, size_t ws_size,
                              hipStream_t stream) {
    const float* z            = (const float*)d_in[0];
    const float* embed        = (const float*)d_in[1];
    const float* cluster_size = (const float*)d_in[2];
    const float* embed_avg    = (const float*)d_in[3];
    float* out = (float*)d_out;
    float* ws  = (float*)d_ws;

    k0_zero<<<(WS_TOTAL + 255) / 256, 256, 0, stream>>>(ws);
    k1_norms<<<(N_ROWS + K_CODES) / 4, 256, 0, stream>>>(z, embed, ws);
    k23_fused<<<N_ROWS / 32, 512, 0, stream>>>(z, embed, ws, out);
    k4a_stats<<<1, 1024, 0, stream>>>(cluster_size, ws, out);
    k4b_embed<<<K_CODES, 256, 0, stream>>>(embed_avg, ws, out);
}

// Round 5
// 543.714 us; speedup vs baseline: 5.8204x; 1.5271x over previous
//
#include <hip/hip_runtime.h>
#include <math.h>

#define N_ROWS 32768
#define DIM 256
#define K_CODES 1024

// ---- workspace float offsets (total ~1.2 MB) ----
#define WS_LOSS   0        // 1024 distributed loss slots
#define WS_NSUM   1024
#define WS_ZZ     2048     // 32768
#define WS_EE     34816    // 1024
#define WS_COUNTS 35840    // 1024
#define WS_ESUM   36864    // 1024*256
#define WS_TOTAL  (36864 + K_CODES * DIM)   // 299008 floats

// ---- output float offsets (return-order concatenation) ----
#define OFF_ZQ    0ull
#define OFF_CODES 8388608ull
#define OFF_LOSS  8421376ull
#define OFF_PERP  8421377ull
#define OFF_ENT   8421378ull
#define OFF_SOFT  8421379ull          // %4==3 -> scalar access in this region
#define OFF_NEMB  41975811ull
#define OFF_NCS   42237955ull
#define OFF_NEA   42238979ull

__global__ __launch_bounds__(256) void k0_zero(float* ws) {
    int i = blockIdx.x * 256 + threadIdx.x;
    if (i < WS_TOTAL) ws[i] = 0.0f;
}

// one wave per row: zz[n]=||z_n||^2 for rows < N_ROWS, ee[k]=||e_k||^2 otherwise
__global__ __launch_bounds__(256) void k1_norms(const float* __restrict__ z,
                                                const float* __restrict__ embed,
                                                float* __restrict__ ws) {
    int wave = threadIdx.x >> 6;
    int lane = threadIdx.x & 63;
    int row = blockIdx.x * 4 + wave;
    const float* src = (row < N_ROWS) ? (z + (size_t)row * DIM)
                                      : (embed + (size_t)(row - N_ROWS) * DIM);
    float4 v = *(const float4*)(src + lane * 4);
    float s = v.x * v.x + v.y * v.y + v.z * v.z + v.w * v.w;
    #pragma unroll
    for (int off = 32; off; off >>= 1) s += __shfl_down(s, off, 64);
    if (lane == 0) {
        if (row < N_ROWS) ws[WS_ZZ + row] = s;
        else              ws[WS_EE + (row - N_ROWS)] = s;
    }
}

// dist GEMM (exact R0 version, known-good 253 us @ 66% VALU):
// dist[n,k] = (zz[n] - 2*z_n.e_k) + ee[k]
// BM=BN=128, BD=32, 256 threads, 8x8 micro-tile per thread.
__global__ __launch_bounds__(256) void k2_dist(const float* __restrict__ z,
                                               const float* __restrict__ embed,
                                               const float* __restrict__ ws,
                                               float* __restrict__ out) {
    __shared__ float As[32][132];
    __shared__ float Bs[32][132];
    int tid = threadIdx.x;
    int tx = tid & 15, ty = tid >> 4;
    int rowBase = blockIdx.y * 128;
    int colBase = blockIdx.x * 128;
    int lr  = tid >> 3;        // 0..31
    int lc4 = (tid & 7) * 4;   // 0,4,...,28

    float acc[8][8];
    #pragma unroll
    for (int i = 0; i < 8; ++i)
        #pragma unroll
        for (int j = 0; j < 8; ++j) acc[i][j] = 0.f;

    for (int dt = 0; dt < 8; ++dt) {
        int d0 = dt * 32;
        #pragma unroll
        for (int i = 0; i < 4; ++i) {
            float4 a = *(const float4*)&z[(size_t)(rowBase + lr + 32 * i) * DIM + d0 + lc4];
            float4 b = *(const float4*)&embed[(size_t)(colBase + lr + 32 * i) * DIM + d0 + lc4];
            As[lc4 + 0][lr + 32 * i] = a.x; As[lc4 + 1][lr + 32 * i] = a.y;
            As[lc4 + 2][lr + 32 * i] = a.z; As[lc4 + 3][lr + 32 * i] = a.w;
            Bs[lc4 + 0][lr + 32 * i] = b.x; Bs[lc4 + 1][lr + 32 * i] = b.y;
            Bs[lc4 + 2][lr + 32 * i] = b.z; Bs[lc4 + 3][lr + 32 * i] = b.w;
        }
        __syncthreads();
        #pragma unroll
        for (int d = 0; d < 32; ++d) {
            float4 a0 = *(const float4*)&As[d][ty * 8];
            float4 a1 = *(const float4*)&As[d][ty * 8 + 4];
            float av[8] = {a0.x, a0.y, a0.z, a0.w, a1.x, a1.y, a1.z, a1.w};
            float bv[8];
            #pragma unroll
            for (int j = 0; j < 8; ++j) bv[j] = Bs[d][tx + 16 * j];
            #pragma unroll
            for (int i = 0; i < 8; ++i)
                #pragma unroll
                for (int j = 0; j < 8; ++j) acc[i][j] += av[i] * bv[j];
        }
        __syncthreads();
    }
    #pragma unroll
    for (int i = 0; i < 8; ++i) {
        int n = rowBase + ty * 8 + i;
        float zzn = ws[WS_ZZ + n];
        float* orow = out + OFF_SOFT + (size_t)n * K_CODES + colBase;
        #pragma unroll
        for (int j = 0; j < 8; ++j) {
            int kk = tx + 16 * j;
            float eek = ws[WS_EE + colBase + kk];
            orow[kk] = (zzn - 2.0f * acc[i][j]) + eek;
        }
    }
}

// R5: wave-per-row softmax/argmin/epilogue. 4 independent waves per block,
// ZERO __syncthreads, pure shfl reductions (old k3: one 256-thread block per
// row with 3 serial block-reductions -> ~200 us; this targets the ~55 us
// traffic floor). Elementwise math identical to the verified k3: same
// argmin lowest-k tiebreak, same 1e-3 tie band + fp64 re-dot, same
// expf((bmin-d)*10) softmax.
__global__ __launch_bounds__(256) void k3_wave(const float* __restrict__ z,
                                               const float* __restrict__ embed,
                                               float* __restrict__ ws,
                                               float* __restrict__ out) {
    int wave = threadIdx.x >> 6;
    int lane = threadIdx.x & 63;
    int n = blockIdx.x * 4 + wave;
    float* dptr = out + OFF_SOFT + (size_t)n * K_CODES;

    // load 16 dists per lane (coalesced dwords; region is only 4B-aligned)
    float d[16];
    float lmin = 3.4e38f; int lidx = 0;
    #pragma unroll
    for (int j = 0; j < 16; ++j) {
        int k = lane + 64 * j;
        d[j] = dptr[k];
        if (d[j] < lmin) { lmin = d[j]; lidx = k; }   // j asc => k asc: keeps lowest k
    }

    // wave argmin with lowest-k tiebreak (associative: tree order immaterial)
    float bmin = lmin; int code = lidx;
    #pragma unroll
    for (int off = 32; off; off >>= 1) {
        float ov = __shfl_down(bmin, off, 64);
        int   oi = __shfl_down(code, off, 64);
        if (ov < bmin || (ov == bmin && oi < code)) { bmin = ov; code = oi; }
    }
    bmin = __shfl(bmin, 0, 64);
    code = __shfl(code, 0, 64);

    // near-tie candidate count (1e-3 band >> fp32 dist error)
    float thr = bmin + 1e-3f;
    int myc = 0;
    #pragma unroll
    for (int j = 0; j < 16; ++j) myc += (d[j] <= thr) ? 1 : 0;
    #pragma unroll
    for (int off = 32; off; off >>= 1) myc += __shfl_down(myc, off, 64);
    int nc = __shfl(myc, 0, 64);

    if (nc > 1) {   // rare path: fp64 re-dot, numpy-style fp32 final rounding
        float zzn = ws[WS_ZZ + n];
        float bestd = 0.f; int bestk = -1; int seen = 0;
        for (int j = 0; j < 16 && seen < 8; ++j) {
            unsigned long long m = __ballot(d[j] <= thr);   // wave-uniform mask
            while (m && seen < 8) {
                int l = __ffsll(m) - 1;
                m &= m - 1;
                int kc = l + 64 * j;
                ++seen;
                double part = 0.0;
                #pragma unroll
                for (int q = 0; q < 4; ++q)
                    part += (double)z[(size_t)n * DIM + lane + 64 * q]
                          * (double)embed[(size_t)kc * DIM + lane + 64 * q];
                #pragma unroll
                for (int off = 32; off; off >>= 1) part += __shfl_down(part, off, 64);
                double dot = __shfl(part, 0, 64);
                float d32 = (zzn - 2.0f * (float)dot) + ws[WS_EE + kc];
                if (bestk < 0 || d32 < bestd || (d32 == bestd && kc < bestk)) { bestd = d32; bestk = kc; }
            }
        }
        code = bestk;   // identical on all lanes
    }

    // softmax (shift by bmin is exact-invariant); overwrite d[] in place
    float s = 0.f;
    #pragma unroll
    for (int j = 0; j < 16; ++j) { d[j] = __expf((bmin - d[j]) * 10.0f); s += d[j]; }
    #pragma unroll
    for (int off = 32; off; off >>= 1) s += __shfl_down(s, off, 64);
    float tot = __shfl(s, 0, 64);
    float inv = 1.0f / tot;
    #pragma unroll
    for (int j = 0; j < 16; ++j) dptr[lane + 64 * j] = d[j] * inv;   // coalesced

    // z_q, commitment loss, EMA scatter: 4 d's per lane, float4
    float4 z4 = *(const float4*)&z[(size_t)n * DIM + lane * 4];
    float4 e4 = *(const float4*)&embed[(size_t)code * DIM + lane * 4];
    *(float4*)&out[OFF_ZQ + (size_t)n * DIM + lane * 4] = e4;
    float dx = z4.x - e4.x, dy = z4.y - e4.y, dz_ = z4.z - e4.z, dw = z4.w - e4.w;
    float lsum = dx * dx + dy * dy + dz_ * dz_ + dw * dw;
    atomicAdd(&ws[WS_ESUM + (size_t)code * DIM + lane * 4 + 0], z4.x);
    atomicAdd(&ws[WS_ESUM + (size_t)code * DIM + lane * 4 + 1], z4.y);
    atomicAdd(&ws[WS_ESUM + (size_t)code * DIM + lane * 4 + 2], z4.z);
    atomicAdd(&ws[WS_ESUM + (size_t)code * DIM + lane * 4 + 3], z4.w);
    #pragma unroll
    for (int off = 32; off; off >>= 1) lsum += __shfl_down(lsum, off, 64);
    if (lane == 0) {
        atomicAdd(&ws[WS_LOSS + (n & 1023)], lsum);   // 1024-way distributed
        atomicAdd(&ws[WS_COUNTS + code], 1.0f);
        out[OFF_CODES + n] = (float)code;
    }
}

__global__ __launch_bounds__(1024) void k4a_stats(const float* __restrict__ cluster_size,
                                                  float* __restrict__ ws,
                                                  float* __restrict__ out) {
    __shared__ float sm[16];
    int k = threadIdx.x;
    int lane = k & 63, wave = k >> 6;
    float cnt = ws[WS_COUNTS + k];
    float ncs = 0.99f * cluster_size[k] + 0.01f * cnt;
    out[OFF_NCS + k] = ncs;

    // nsum
    float v = ncs;
    #pragma unroll
    for (int off = 32; off; off >>= 1) v += __shfl_down(v, off, 64);
    if (lane == 0) sm[wave] = v;
    __syncthreads();
    if (k == 0) {
        float t = 0.f;
        for (int w = 0; w < 16; ++w) t += sm[w];
        ws[WS_NSUM] = t;
    }
    __syncthreads();

    // entropy
    float avg = cnt / (float)N_ROWS;
    v = -avg * logf(avg + 1e-10f);
    #pragma unroll
    for (int off = 32; off; off >>= 1) v += __shfl_down(v, off, 64);
    if (lane == 0) sm[wave] = v;
    __syncthreads();
    if (k == 0) {
        float ent = 0.f;
        for (int w = 0; w < 16; ++w) ent += sm[w];
        out[OFF_ENT]  = ent;
        out[OFF_PERP] = expf(ent);
    }
    __syncthreads();

    // loss: sum the 1024 distributed slots
    v = ws[WS_LOSS + k];
    #pragma unroll
    for (int off = 32; off; off >>= 1) v += __shfl_down(v, off, 64);
    if (lane == 0) sm[wave] = v;
    __syncthreads();
    if (k == 0) {
        float t = 0.f;
        for (int w = 0; w < 16; ++w) t += sm[w];
        out[OFF_LOSS] = t / 8388608.0f;
    }
}

__global__ __launch_bounds__(256) void k4b_embed(const float* __restrict__ embed_avg,
                                                 const float* __restrict__ ws,
                                                 float* __restrict__ out) {
    int k = blockIdx.x, d = threadIdx.x;
    float es  = ws[WS_ESUM + (size_t)k * DIM + d];
    float nea = 0.99f * embed_avg[(size_t)k * DIM + d] + 0.01f * es;
    out[OFF_NEA + (size_t)k * DIM + d] = nea;
    float ncs  = out[OFF_NCS + k];
    float nsum = ws[WS_NSUM];
    float csn  = (ncs + 1e-5f) / (nsum + K_CODES * 1e-5f) * nsum;
    out[OFF_NEMB + (size_t)k * DIM + d] = nea / csn;
}

extern "C" void kernel_launch(void* const* d_in, const int* in_sizes, int n_in,
                              void* d_out, int out_size, void* d_ws, size_t ws_size,
                              hipStream_t stream) {
    const float* z            = (const float*)d_in[0];
    const float* embed        = (const float*)d_in[1];
    const float* cluster_size = (const float*)d_in[2];
    const float* embed_avg    = (const float*)d_in[3];
    float* out = (float*)d_out;
    float* ws  = (float*)d_ws;

    k0_zero<<<(WS_TOTAL + 255) / 256, 256, 0, stream>>>(ws);
    k1_norms<<<(N_ROWS + K_CODES) / 4, 256, 0, stream>>>(z, embed, ws);
    k2_dist<<<dim3(8, 256), 256, 0, stream>>>(z, embed, ws, out);
    k3_wave<<<N_ROWS / 4, 256, 0, stream>>>(z, embed, ws, out);
    k4a_stats<<<1, 1024, 0, stream>>>(cluster_size, ws, out);
    k4b_embed<<<K_CODES, 256, 0, stream>>>(embed_avg, ws, out);
}

// Round 6
// 430.811 us; speedup vs baseline: 7.3458x; 1.2621x over previous
//
#include <hip/hip_runtime.h>
#include <math.h>

#define N_ROWS 32768
#define DIM 256
#define K_CODES 1024

// ---- workspace float offsets (total ~1.2 MB) ----
#define WS_LOSS   0        // 1024 distributed loss slots
#define WS_NSUM   1024
#define WS_ZZ     2048     // 32768
#define WS_EE     34816    // 1024
#define WS_COUNTS 35840    // 1024
#define WS_ESUM   36864    // 1024*256
#define WS_TOTAL  (36864 + K_CODES * DIM)   // 299008 floats

// ---- output float offsets (return-order concatenation) ----
#define OFF_ZQ    0ull
#define OFF_CODES 8388608ull
#define OFF_LOSS  8421376ull
#define OFF_PERP  8421377ull
#define OFF_ENT   8421378ull
#define OFF_SOFT  8421379ull          // %4==3 -> scalar access in this region
#define OFF_NEMB  41975811ull
#define OFF_NCS   42237955ull
#define OFF_NEA   42238979ull

// Scratch-in-out plan (regions consumed BEFORE their real writer runs):
//   z_hi/z_lo bf16 planes -> OFF_ZQ region (33.5 MB, exact fit); k3 writes zq after k2.
//   e_hi/e_lo bf16 planes -> OFF_NEMB region (1 MB, exact fit); k4b writes it last.

typedef __attribute__((ext_vector_type(8))) short bf16x8;   // 8 bf16 (4 VGPRs)
typedef __attribute__((ext_vector_type(4))) float f32x4;

__device__ __forceinline__ ushort f2bf(float x) {           // fp32 -> bf16 RNE
    union { float f; unsigned u; } a; a.f = x;
    unsigned r = a.u + 0x7fffu + ((a.u >> 16) & 1u);
    return (ushort)(r >> 16);
}
__device__ __forceinline__ float bf2f(ushort h) {
    union { unsigned u; float f; } a; a.u = ((unsigned)h) << 16;
    return a.f;
}

__global__ __launch_bounds__(256) void k0_zero(float* ws) {
    int i = blockIdx.x * 256 + threadIdx.x;
    if (i < WS_TOTAL) ws[i] = 0.0f;
}

// one wave per row: norms AND split-bf16 plane extraction (hi = bf16(x),
// lo = bf16(x - hi)); folded here since k1 already streams z and embed.
__global__ __launch_bounds__(256) void k1_norms(const float* __restrict__ z,
                                                const float* __restrict__ embed,
                                                float* __restrict__ ws,
                                                float* out) {
    ushort* zhi = (ushort*)(out + OFF_ZQ);
    ushort* zlo = zhi + (size_t)N_ROWS * DIM;
    ushort* ehi = (ushort*)(out + OFF_NEMB);
    ushort* elo = ehi + (size_t)K_CODES * DIM;

    int wave = threadIdx.x >> 6;
    int lane = threadIdx.x & 63;
    int row = blockIdx.x * 4 + wave;
    const float* src = (row < N_ROWS) ? (z + (size_t)row * DIM)
                                      : (embed + (size_t)(row - N_ROWS) * DIM);
    float4 v = *(const float4*)(src + lane * 4);
    float s = v.x * v.x + v.y * v.y + v.z * v.z + v.w * v.w;

    ushort h0 = f2bf(v.x), h1 = f2bf(v.y), h2 = f2bf(v.z), h3 = f2bf(v.w);
    ushort l0 = f2bf(v.x - bf2f(h0)), l1 = f2bf(v.y - bf2f(h1));
    ushort l2 = f2bf(v.z - bf2f(h2)), l3 = f2bf(v.w - bf2f(h3));
    unsigned hA = (unsigned)h0 | ((unsigned)h1 << 16);
    unsigned hB = (unsigned)h2 | ((unsigned)h3 << 16);
    unsigned lA = (unsigned)l0 | ((unsigned)l1 << 16);
    unsigned lB = (unsigned)l2 | ((unsigned)l3 << 16);

    if (row < N_ROWS) {
        size_t o = (size_t)row * DIM + lane * 4;
        ((uint2*)(zhi + o))[0] = make_uint2(hA, hB);   // 8B-aligned
        ((uint2*)(zlo + o))[0] = make_uint2(lA, lB);
    } else {
        size_t o = (size_t)(row - N_ROWS) * DIM + lane * 4;
        unsigned* ph = (unsigned*)(ehi + o);           // base only 4B-aligned
        unsigned* pl = (unsigned*)(elo + o);
        ph[0] = hA; ph[1] = hB;
        pl[0] = lA; pl[1] = lB;
    }

    #pragma unroll
    for (int off = 32; off; off >>= 1) s += __shfl_down(s, off, 64);
    if (lane == 0) {
        if (row < N_ROWS) ws[WS_ZZ + row] = s;
        else              ws[WS_EE + (row - N_ROWS)] = s;
    }
}

// R6: dist GEMM on matrix cores via split-bf16 (3 products: hh + hl + lh;
// dropped lo*lo ~1e-5 abs on dist, 100x under the 1e-3 tie band).
// Block = 256 thr (4 waves, 2x2), tile 64 rows x 256 cols, no LDS, no barriers.
// mfma_f32_16x16x32_bf16; A/B use the SAME lane->k map so any intra-lane
// k-permutation cancels between A and B; C/D layout per m89-verified mapping
// (col = lane&15, row = (lane>>4)*4 + reg).
__global__ __launch_bounds__(256, 3) void k2_mfma(const float* __restrict__ ws,
                                                  float* out) {
    const ushort* zhi = (const ushort*)(out + OFF_ZQ);
    const ushort* zlo = zhi + (size_t)N_ROWS * DIM;
    const ushort* ehi = (const ushort*)(out + OFF_NEMB);
    const ushort* elo = ehi + (size_t)K_CODES * DIM;

    int tid  = threadIdx.x;
    int lane = tid & 63;
    int wid  = tid >> 6;
    int wr   = wid >> 1, wc = wid & 1;
    int rowBase = blockIdx.y * 64 + wr * 32;
    int colBase = blockIdx.x * 256 + wc * 128;
    int l15 = lane & 15, lg = lane >> 4;
    int kof = lg * 8;

    f32x4 acc[2][8];
    #pragma unroll
    for (int fi = 0; fi < 2; ++fi)
        #pragma unroll
        for (int fj = 0; fj < 8; ++fj)
            acc[fi][fj] = (f32x4){0.f, 0.f, 0.f, 0.f};

    for (int kk = 0; kk < DIM; kk += 32) {
        bf16x8 ah[2], al[2];
        #pragma unroll
        for (int fi = 0; fi < 2; ++fi) {
            size_t ao = (size_t)(rowBase + fi * 16 + l15) * DIM + kk + kof;
            ah[fi] = *(const bf16x8*)(zhi + ao);   // 16B-aligned dwordx4
            al[fi] = *(const bf16x8*)(zlo + ao);
        }
        #pragma unroll
        for (int fj = 0; fj < 8; ++fj) {
            size_t bo = (size_t)(colBase + fj * 16 + l15) * DIM + kk + kof;
            union { unsigned u[4]; bf16x8 v; } bh, bl;
            const unsigned* ph = (const unsigned*)(ehi + bo);  // 4B-aligned region
            const unsigned* pl = (const unsigned*)(elo + bo);
            bh.u[0] = ph[0]; bh.u[1] = ph[1]; bh.u[2] = ph[2]; bh.u[3] = ph[3];
            bl.u[0] = pl[0]; bl.u[1] = pl[1]; bl.u[2] = pl[2]; bl.u[3] = pl[3];
            #pragma unroll
            for (int fi = 0; fi < 2; ++fi) {
                acc[fi][fj] = __builtin_amdgcn_mfma_f32_16x16x32_bf16(ah[fi], bh.v, acc[fi][fj], 0, 0, 0);
                acc[fi][fj] = __builtin_amdgcn_mfma_f32_16x16x32_bf16(ah[fi], bl.v, acc[fi][fj], 0, 0, 0);
                acc[fi][fj] = __builtin_amdgcn_mfma_f32_16x16x32_bf16(al[fi], bh.v, acc[fi][fj], 0, 0, 0);
            }
        }
    }

    // epilogue: dist = (zz - 2*dot) + ee  (same expression as verified k2)
    #pragma unroll
    for (int fi = 0; fi < 2; ++fi) {
        #pragma unroll
        for (int q = 0; q < 4; ++q) {
            int n = rowBase + fi * 16 + lg * 4 + q;
            float zzn = ws[WS_ZZ + n];
            float* orow = out + OFF_SOFT + (size_t)n * K_CODES;
            #pragma unroll
            for (int fj = 0; fj < 8; ++fj) {
                int k = colBase + fj * 16 + l15;
                orow[k] = (zzn - 2.0f * acc[fi][fj][q]) + ws[WS_EE + k];
            }
        }
    }
}

__device__ inline void blockMinIdx(float& v, int& idx, float* smv, int* smi) {
    int lane = threadIdx.x & 63, wave = threadIdx.x >> 6;
    #pragma unroll
    for (int off = 32; off; off >>= 1) {
        float ov = __shfl_down(v, off, 64);
        int   oi = __shfl_down(idx, off, 64);
        if (ov < v || (ov == v && oi < idx)) { v = ov; idx = oi; }
    }
    if (lane == 0) { smv[wave] = v; smi[wave] = idx; }
    __syncthreads();
    v = smv[0]; idx = smi[0];
    #pragma unroll
    for (int w = 1; w < 4; ++w) {
        float ov = smv[w]; int oi = smi[w];
        if (ov < v || (ov == v && oi < idx)) { v = ov; idx = oi; }
    }
    __syncthreads();
}

__device__ inline float blockSum(float v, float* sm) {
    int lane = threadIdx.x & 63, wave = threadIdx.x >> 6;
    #pragma unroll
    for (int off = 32; off; off >>= 1) v += __shfl_down(v, off, 64);
    if (lane == 0) sm[wave] = v;
    __syncthreads();
    float r = sm[0] + sm[1] + sm[2] + sm[3];
    __syncthreads();
    return r;
}

// per-row block (exact R0 version, known-good ~190 us).
__global__ __launch_bounds__(256) void k3_softmax(const float* __restrict__ z,
                                                  const float* __restrict__ embed,
                                                  float* __restrict__ ws,
                                                  float* __restrict__ out) {
    __shared__ float smv[4];
    __shared__ int   smi[4];
    __shared__ float sms[4];
    __shared__ double sdd[4];
    __shared__ int cand[8];
    __shared__ int ncand;

    int n = blockIdx.x;
    int tid = threadIdx.x;
    float* dptr = out + OFF_SOFT + (size_t)n * K_CODES;

    float d[4];
    float lmin = 3.4e38f; int lidx = 0;
    #pragma unroll
    for (int j = 0; j < 4; ++j) {
        int k = tid + 256 * j;
        d[j] = dptr[k];
        if (d[j] < lmin) { lmin = d[j]; lidx = k; }
    }
    float bmin = lmin; int code = lidx;
    blockMinIdx(bmin, code, smv, smi);

    // near-tie candidates: anything within 1e-3 of min (>> dist error ~1e-4)
    if (tid == 0) ncand = 0;
    __syncthreads();
    #pragma unroll
    for (int j = 0; j < 4; ++j) {
        if (d[j] <= bmin + 1e-3f) {
            int slot = atomicAdd(&ncand, 1);
            if (slot < 8) cand[slot] = tid + 256 * j;
        }
    }
    __syncthreads();
    int nc = ncand;
    float zv = z[(size_t)n * DIM + tid];
    if (nc > 1) {   // rare path: refine with fp64 dot, numpy-style fp32 final rounding
        int lim = nc < 8 ? nc : 8;
        float zzn = ws[WS_ZZ + n];
        float bestd = 0.f; int bestk = -1;
        for (int c = 0; c < lim; ++c) {
            int kc = cand[c];
            double part = (double)zv * (double)embed[(size_t)kc * DIM + tid];
            int lane = tid & 63, wave = tid >> 6;
            #pragma unroll
            for (int off = 32; off; off >>= 1) part += __shfl_down(part, off, 64);
            if (lane == 0) sdd[wave] = part;
            __syncthreads();
            double dot = sdd[0] + sdd[1] + sdd[2] + sdd[3];
            __syncthreads();
            float d32 = (zzn - 2.0f * (float)dot) + ws[WS_EE + kc];
            if (bestk < 0 || d32 < bestd || (d32 == bestd && kc < bestk)) { bestd = d32; bestk = kc; }
        }
        code = bestk;   // identical on all threads
    }

    // softmax (shift by bmin is exact-invariant)
    float p[4]; float s = 0.f;
    #pragma unroll
    for (int j = 0; j < 4; ++j) { p[j] = __expf((bmin - d[j]) * 10.0f); s += p[j]; }
    float tot = blockSum(s, sms);
    float inv = 1.0f / tot;
    #pragma unroll
    for (int j = 0; j < 4; ++j) dptr[tid + 256 * j] = p[j] * inv;

    float qv = embed[(size_t)code * DIM + tid];
    out[OFF_ZQ + (size_t)n * DIM + tid] = qv;
    float diff = zv - qv;
    float lsum = blockSum(diff * diff, sms);
    atomicAdd(&ws[WS_ESUM + (size_t)code * DIM + tid], zv);
    if (tid == 0) {
        atomicAdd(&ws[WS_LOSS + (n & 1023)], lsum);   // 1024-way distributed
        atomicAdd(&ws[WS_COUNTS + code], 1.0f);
        out[OFF_CODES + n] = (float)code;
    }
}

__global__ __launch_bounds__(1024) void k4a_stats(const float* __restrict__ cluster_size,
                                                  float* __restrict__ ws,
                                                  float* __restrict__ out) {
    __shared__ float sm[16];
    int k = threadIdx.x;
    int lane = k & 63, wave = k >> 6;
    float cnt = ws[WS_COUNTS + k];
    float ncs = 0.99f * cluster_size[k] + 0.01f * cnt;
    out[OFF_NCS + k] = ncs;

    // nsum
    float v = ncs;
    #pragma unroll
    for (int off = 32; off; off >>= 1) v += __shfl_down(v, off, 64);
    if (lane == 0) sm[wave] = v;
    __syncthreads();
    if (k == 0) {
        float t = 0.f;
        for (int w = 0; w < 16; ++w) t += sm[w];
        ws[WS_NSUM] = t;
    }
    __syncthreads();

    // entropy
    float avg = cnt / (float)N_ROWS;
    v = -avg * logf(avg + 1e-10f);
    #pragma unroll
    for (int off = 32; off; off >>= 1) v += __shfl_down(v, off, 64);
    if (lane == 0) sm[wave] = v;
    __syncthreads();
    if (k == 0) {
        float ent = 0.f;
        for (int w = 0; w < 16; ++w) ent += sm[w];
        out[OFF_ENT]  = ent;
        out[OFF_PERP] = expf(ent);
    }
    __syncthreads();

    // loss: sum the 1024 distributed slots
    v = ws[WS_LOSS + k];
    #pragma unroll
    for (int off = 32; off; off >>= 1) v += __shfl_down(v, off, 64);
    if (lane == 0) sm[wave] = v;
    __syncthreads();
    if (k == 0) {
        float t = 0.f;
        for (int w = 0; w < 16; ++w) t += sm[w];
        out[OFF_LOSS] = t / 8388608.0f;
    }
}

__global__ __launch_bounds__(256) void k4b_embed(const float* __restrict__ embed_avg,
                                                 const float* __restrict__ ws,
                                                 float* __restrict__ out) {
    int k = blockIdx.x, d = threadIdx.x;
    float es  = ws[WS_ESUM + (size_t)k * DIM + d];
    float nea = 0.99f * embed_avg[(size_t)k * DIM + d] + 0.01f * es;
    out[OFF_NEA + (size_t)k * DIM + d] = nea;
    float ncs  = out[OFF_NCS + k];
    float nsum = ws[WS_NSUM];
    float csn  = (ncs + 1e-5f) / (nsum + K_CODES * 1e-5f) * nsum;
    out[OFF_NEMB + (size_t)k * DIM + d] = nea / csn;
}

extern "C" void kernel_launch(void* const* d_in, const int* in_sizes, int n_in,
                              void* d_out, int out_size, void* d_ws, size_t ws_size,
                              hipStream_t stream) {
    const float* z            = (const float*)d_in[0];
    const float* embed        = (const float*)d_in[1];
    const float* cluster_size = (const float*)d_in[2];
    const float* embed_avg    = (const float*)d_in[3];
    float* out = (float*)d_out;
    float* ws  = (float*)d_ws;

    k0_zero<<<(WS_TOTAL + 255) / 256, 256, 0, stream>>>(ws);
    k1_norms<<<(N_ROWS + K_CODES) / 4, 256, 0, stream>>>(z, embed, ws, out);
    k2_mfma<<<dim3(K_CODES / 256, N_ROWS / 64), 256, 0, stream>>>(ws, out);
    k3_softmax<<<N_ROWS, 256, 0, stream>>>(z, embed, ws, out);
    k4a_stats<<<1, 1024, 0, stream>>>(cluster_size, ws, out);
    k4b_embed<<<K_CODES, 256, 0, stream>>>(embed_avg, ws, out);
}

// Round 7
// 369.388 us; speedup vs baseline: 8.5672x; 1.1663x over previous
//
#include <hip/hip_runtime.h>
#include <math.h>

#define N_ROWS 32768
#define DIM 256
#define K_CODES 1024

// ---- workspace float offsets (total ~1.2 MB) ----
#define WS_LOSS   0        // 1024 distributed loss slots
#define WS_NSUM   1024
#define WS_ZZ     2048     // 32768
#define WS_EE     34816    // 1024
#define WS_COUNTS 35840    // 1024
#define WS_ESUM   36864    // 1024*256
#define WS_TOTAL  (36864 + K_CODES * DIM)   // 299008 floats

// ---- output float offsets (return-order concatenation) ----
#define OFF_ZQ    0ull
#define OFF_CODES 8388608ull
#define OFF_LOSS  8421376ull
#define OFF_PERP  8421377ull
#define OFF_ENT   8421378ull
#define OFF_SOFT  8421379ull          // %4==3 -> scalar access in this region
#define OFF_NEMB  41975811ull
#define OFF_NCS   42237955ull
#define OFF_NEA   42238979ull

// Scratch-in-out plan (regions consumed BEFORE their real writer runs):
//   packed z hi/lo planes -> OFF_ZQ region (33.55 MB exact fit); k3 rewrites zq.
//   packed e hi/lo planes -> OFF_EPACK = OFF_NEMB+1 (16B-aligned; 1 MB spills
//   one float into the NCS region, which k4a overwrites AFTER k2 consumed it).
#define OFF_EPACK 41975812ull
#define PLANE_Z   8388608ull    // 32768*256 bf16 elements per z plane
#define PLANE_E   262144ull     // 1024*256 bf16 elements per e plane

// Fragment-native packed layout (per plane), unit = bf16 element:
//   idx(row,k) = ((row>>4)*8 + (k>>5))*512 + ((((k>>3)&3)*16 + (row&15))*8) + (k&7)
// i.e. each (16-row x 32-k) fragment block is 512 elements = 1 KB, stored as
// lane-major slots of 8 elements; k2's wave fragment load = 64 lanes x 16B
// contiguous (single coalesced dwordx4 per lane).

typedef __attribute__((ext_vector_type(8))) short bf16x8;   // 8 bf16 (4 VGPRs)
typedef __attribute__((ext_vector_type(4))) float f32x4;

__device__ __forceinline__ ushort f2bf(float x) {           // fp32 -> bf16 RNE
    union { float f; unsigned u; } a; a.f = x;
    unsigned r = a.u + 0x7fffu + ((a.u >> 16) & 1u);
    return (ushort)(r >> 16);
}
__device__ __forceinline__ float bf2f(ushort h) {
    union { unsigned u; float f; } a; a.u = ((unsigned)h) << 16;
    return a.f;
}

__global__ __launch_bounds__(256) void k0_zero(float* ws) {
    int i = blockIdx.x * 256 + threadIdx.x;
    if (i < WS_TOTAL) ws[i] = 0.0f;
}

// one wave per row: norms AND split-bf16 plane extraction in packed
// fragment-native layout. Lane L holds k = 4L..4L+3 of its row.
__global__ __launch_bounds__(256) void k1_norms(const float* __restrict__ z,
                                                const float* __restrict__ embed,
                                                float* __restrict__ ws,
                                                float* out) {
    ushort* zhi = (ushort*)(out + OFF_ZQ);
    ushort* zlo = zhi + PLANE_Z;
    ushort* ehi = (ushort*)(out + OFF_EPACK);
    ushort* elo = ehi + PLANE_E;

    int wave = threadIdx.x >> 6;
    int lane = threadIdx.x & 63;
    int row = blockIdx.x * 4 + wave;
    const float* src = (row < N_ROWS) ? (z + (size_t)row * DIM)
                                      : (embed + (size_t)(row - N_ROWS) * DIM);
    float4 v = *(const float4*)(src + lane * 4);
    float s = v.x * v.x + v.y * v.y + v.z * v.z + v.w * v.w;

    ushort h0 = f2bf(v.x), h1 = f2bf(v.y), h2 = f2bf(v.z), h3 = f2bf(v.w);
    ushort l0 = f2bf(v.x - bf2f(h0)), l1 = f2bf(v.y - bf2f(h1));
    ushort l2 = f2bf(v.z - bf2f(h2)), l3 = f2bf(v.w - bf2f(h3));
    unsigned hA = (unsigned)h0 | ((unsigned)h1 << 16);
    unsigned hB = (unsigned)h2 | ((unsigned)h3 << 16);
    unsigned lA = (unsigned)l0 | ((unsigned)l1 << 16);
    unsigned lB = (unsigned)l2 | ((unsigned)l3 << 16);

    // packed index for this lane's 4-element k-run (j0 = (4L)&7 in {0,4}):
    int r = (row < N_ROWS) ? row : (row - N_ROWS);
    int kb = lane >> 3;                 // (4L)>>5
    int lg = (lane >> 1) & 3;           // ((4L)>>3)&3
    int j0 = (lane & 1) * 4;            // (4L)&7
    size_t idx = ((size_t)(r >> 4) * 8 + kb) * 512
               + (size_t)(lg * 16 + (r & 15)) * 8 + j0;   // 8B-aligned

    if (row < N_ROWS) {
        *(uint2*)(zhi + idx) = make_uint2(hA, hB);
        *(uint2*)(zlo + idx) = make_uint2(lA, lB);
    } else {
        *(uint2*)(ehi + idx) = make_uint2(hA, hB);
        *(uint2*)(elo + idx) = make_uint2(lA, lB);
    }

    #pragma unroll
    for (int off = 32; off; off >>= 1) s += __shfl_down(s, off, 64);
    if (lane == 0) {
        if (row < N_ROWS) ws[WS_ZZ + row] = s;
        else              ws[WS_EE + (row - N_ROWS)] = s;
    }
}

// R7: dist GEMM on matrix cores, split-bf16 (hh + hl + lh), packed planes.
// Identical MFMA sequence / lane maps / epilogue to the verified R6 kernel;
// only fragment ADDRESSES changed (packed -> every load one coalesced dwordx4,
// 20 VMEM per K-step instead of 68, no scalar-dword decomposition).
// Block = 256 thr (4 waves 2x2), tile 64 rows x 256 cols, no LDS, no barriers.
__global__ __launch_bounds__(256, 3) void k2_mfma(const float* __restrict__ ws,
                                                  float* out) {
    const ushort* zhi = (const ushort*)(out + OFF_ZQ);
    const ushort* ehi = (const ushort*)(out + OFF_EPACK);

    int tid  = threadIdx.x;
    int lane = tid & 63;
    int wid  = tid >> 6;
    int wr   = wid >> 1, wc = wid & 1;
    int rowBase = blockIdx.y * 64 + wr * 32;
    int colBase = blockIdx.x * 256 + wc * 128;
    int l15 = lane & 15, lg = lane >> 4;

    f32x4 acc[2][8];
    #pragma unroll
    for (int fi = 0; fi < 2; ++fi)
        #pragma unroll
        for (int fj = 0; fj < 8; ++fj)
            acc[fi][fj] = (f32x4){0.f, 0.f, 0.f, 0.f};

    int rowBlk = rowBase >> 4;          // multiple of 2
    int colBlk = colBase >> 4;          // multiple of 8

    for (int kb = 0; kb < 8; ++kb) {    // K-blocks of 32
        bf16x8 ah[2], al[2];
        #pragma unroll
        for (int fi = 0; fi < 2; ++fi) {
            const ushort* pa = zhi + ((size_t)(rowBlk + fi) * 8 + kb) * 512 + lane * 8;
            ah[fi] = *(const bf16x8*)pa;
            al[fi] = *(const bf16x8*)(pa + PLANE_Z);
        }
        #pragma unroll
        for (int fj = 0; fj < 8; ++fj) {
            const ushort* pb = ehi + ((size_t)(colBlk + fj) * 8 + kb) * 512 + lane * 8;
            bf16x8 bh = *(const bf16x8*)pb;
            bf16x8 bl = *(const bf16x8*)(pb + PLANE_E);
            #pragma unroll
            for (int fi = 0; fi < 2; ++fi) {
                acc[fi][fj] = __builtin_amdgcn_mfma_f32_16x16x32_bf16(ah[fi], bh, acc[fi][fj], 0, 0, 0);
                acc[fi][fj] = __builtin_amdgcn_mfma_f32_16x16x32_bf16(ah[fi], bl, acc[fi][fj], 0, 0, 0);
                acc[fi][fj] = __builtin_amdgcn_mfma_f32_16x16x32_bf16(al[fi], bh, acc[fi][fj], 0, 0, 0);
            }
        }
    }

    // epilogue: dist = (zz - 2*dot) + ee  (same expression as verified k2)
    // C/D layout (m89-verified): col = lane&15, row = (lane>>4)*4 + reg
    #pragma unroll
    for (int fi = 0; fi < 2; ++fi) {
        #pragma unroll
        for (int q = 0; q < 4; ++q) {
            int n = rowBase + fi * 16 + lg * 4 + q;
            float zzn = ws[WS_ZZ + n];
            float* orow = out + OFF_SOFT + (size_t)n * K_CODES;
            #pragma unroll
            for (int fj = 0; fj < 8; ++fj) {
                int k = colBase + fj * 16 + l15;
                orow[k] = (zzn - 2.0f * acc[fi][fj][q]) + ws[WS_EE + k];
            }
        }
    }
}

__device__ inline void blockMinIdx(float& v, int& idx, float* smv, int* smi) {
    int lane = threadIdx.x & 63, wave = threadIdx.x >> 6;
    #pragma unroll
    for (int off = 32; off; off >>= 1) {
        float ov = __shfl_down(v, off, 64);
        int   oi = __shfl_down(idx, off, 64);
        if (ov < v || (ov == v && oi < idx)) { v = ov; idx = oi; }
    }
    if (lane == 0) { smv[wave] = v; smi[wave] = idx; }
    __syncthreads();
    v = smv[0]; idx = smi[0];
    #pragma unroll
    for (int w = 1; w < 4; ++w) {
        float ov = smv[w]; int oi = smi[w];
        if (ov < v || (ov == v && oi < idx)) { v = ov; idx = oi; }
    }
    __syncthreads();
}

__device__ inline float blockSum(float v, float* sm) {
    int lane = threadIdx.x & 63, wave = threadIdx.x >> 6;
    #pragma unroll
    for (int off = 32; off; off >>= 1) v += __shfl_down(v, off, 64);
    if (lane == 0) sm[wave] = v;
    __syncthreads();
    float r = sm[0] + sm[1] + sm[2] + sm[3];
    __syncthreads();
    return r;
}

// per-row block (exact R0 version, known-good ~190 us).
__global__ __launch_bounds__(256) void k3_softmax(const float* __restrict__ z,
                                                  const float* __restrict__ embed,
                                                  float* __restrict__ ws,
                                                  float* __restrict__ out) {
    __shared__ float smv[4];
    __shared__ int   smi[4];
    __shared__ float sms[4];
    __shared__ double sdd[4];
    __shared__ int cand[8];
    __shared__ int ncand;

    int n = blockIdx.x;
    int tid = threadIdx.x;
    float* dptr = out + OFF_SOFT + (size_t)n * K_CODES;

    float d[4];
    float lmin = 3.4e38f; int lidx = 0;
    #pragma unroll
    for (int j = 0; j < 4; ++j) {
        int k = tid + 256 * j;
        d[j] = dptr[k];
        if (d[j] < lmin) { lmin = d[j]; lidx = k; }
    }
    float bmin = lmin; int code = lidx;
    blockMinIdx(bmin, code, smv, smi);

    // near-tie candidates: anything within 1e-3 of min (>> dist error ~1e-4)
    if (tid == 0) ncand = 0;
    __syncthreads();
    #pragma unroll
    for (int j = 0; j < 4; ++j) {
        if (d[j] <= bmin + 1e-3f) {
            int slot = atomicAdd(&ncand, 1);
            if (slot < 8) cand[slot] = tid + 256 * j;
        }
    }
    __syncthreads();
    int nc = ncand;
    float zv = z[(size_t)n * DIM + tid];
    if (nc > 1) {   // rare path: refine with fp64 dot, numpy-style fp32 final rounding
        int lim = nc < 8 ? nc : 8;
        float zzn = ws[WS_ZZ + n];
        float bestd = 0.f; int bestk = -1;
        for (int c = 0; c < lim; ++c) {
            int kc = cand[c];
            double part = (double)zv * (double)embed[(size_t)kc * DIM + tid];
            int lane = tid & 63, wave = tid >> 6;
            #pragma unroll
            for (int off = 32; off; off >>= 1) part += __shfl_down(part, off, 64);
            if (lane == 0) sdd[wave] = part;
            __syncthreads();
            double dot = sdd[0] + sdd[1] + sdd[2] + sdd[3];
            __syncthreads();
            float d32 = (zzn - 2.0f * (float)dot) + ws[WS_EE + kc];
            if (bestk < 0 || d32 < bestd || (d32 == bestd && kc < bestk)) { bestd = d32; bestk = kc; }
        }
        code = bestk;   // identical on all threads
    }

    // softmax (shift by bmin is exact-invariant)
    float p[4]; float s = 0.f;
    #pragma unroll
    for (int j = 0; j < 4; ++j) { p[j] = __expf((bmin - d[j]) * 10.0f); s += p[j]; }
    float tot = blockSum(s, sms);
    float inv = 1.0f / tot;
    #pragma unroll
    for (int j = 0; j < 4; ++j) dptr[tid + 256 * j] = p[j] * inv;

    float qv = embed[(size_t)code * DIM + tid];
    out[OFF_ZQ + (size_t)n * DIM + tid] = qv;
    float diff = zv - qv;
    float lsum = blockSum(diff * diff, sms);
    atomicAdd(&ws[WS_ESUM + (size_t)code * DIM + tid], zv);
    if (tid == 0) {
        atomicAdd(&ws[WS_LOSS + (n & 1023)], lsum);   // 1024-way distributed
        atomicAdd(&ws[WS_COUNTS + code], 1.0f);
        out[OFF_CODES + n] = (float)code;
    }
}

__global__ __launch_bounds__(1024) void k4a_stats(const float* __restrict__ cluster_size,
                                                  float* __restrict__ ws,
                                                  float* __restrict__ out) {
    __shared__ float sm[16];
    int k = threadIdx.x;
    int lane = k & 63, wave = k >> 6;
    float cnt = ws[WS_COUNTS + k];
    float ncs = 0.99f * cluster_size[k] + 0.01f * cnt;
    out[OFF_NCS + k] = ncs;

    // nsum
    float v = ncs;
    #pragma unroll
    for (int off = 32; off; off >>= 1) v += __shfl_down(v, off, 64);
    if (lane == 0) sm[wave] = v;
    __syncthreads();
    if (k == 0) {
        float t = 0.f;
        for (int w = 0; w < 16; ++w) t += sm[w];
        ws[WS_NSUM] = t;
    }
    __syncthreads();

    // entropy
    float avg = cnt / (float)N_ROWS;
    v = -avg * logf(avg + 1e-10f);
    #pragma unroll
    for (int off = 32; off; off >>= 1) v += __shfl_down(v, off, 64);
    if (lane == 0) sm[wave] = v;
    __syncthreads();
    if (k == 0) {
        float ent = 0.f;
        for (int w = 0; w < 16; ++w) ent += sm[w];
        out[OFF_ENT]  = ent;
        out[OFF_PERP] = expf(ent);
    }
    __syncthreads();

    // loss: sum the 1024 distributed slots
    v = ws[WS_LOSS + k];
    #pragma unroll
    for (int off = 32; off; off >>= 1) v += __shfl_down(v, off, 64);
    if (lane == 0) sm[wave] = v;
    __syncthreads();
    if (k == 0) {
        float t = 0.f;
        for (int w = 0; w < 16; ++w) t += sm[w];
        out[OFF_LOSS] = t / 8388608.0f;
    }
}

__global__ __launch_bounds__(256) void k4b_embed(const float* __restrict__ embed_avg,
                                                 const float* __restrict__ ws,
                                                 float* __restrict__ out) {
    int k = blockIdx.x, d = threadIdx.x;
    float es  = ws[WS_ESUM + (size_t)k * DIM + d];
    float nea = 0.99f * embed_avg[(size_t)k * DIM + d] + 0.01f * es;
    out[OFF_NEA + (size_t)k * DIM + d] = nea;
    float ncs  = out[OFF_NCS + k];
    float nsum = ws[WS_NSUM];
    float csn  = (ncs + 1e-5f) / (nsum + K_CODES * 1e-5f) * nsum;
    out[OFF_NEMB + (size_t)k * DIM + d] = nea / csn;
}

extern "C" void kernel_launch(void* const* d_in, const int* in_sizes, int n_in,
                              void* d_out, int out_size, void* d_ws, size_t ws_size,
                              hipStream_t stream) {
    const float* z            = (const float*)d_in[0];
    const float* embed        = (const float*)d_in[1];
    const float* cluster_size = (const float*)d_in[2];
    const float* embed_avg    = (const float*)d_in[3];
    float* out = (float*)d_out;
    float* ws  = (float*)d_ws;

    k0_zero<<<(WS_TOTAL + 255) / 256, 256, 0, stream>>>(ws);
    k1_norms<<<(N_ROWS + K_CODES) / 4, 256, 0, stream>>>(z, embed, ws, out);
    k2_mfma<<<dim3(K_CODES / 256, N_ROWS / 64), 256, 0, stream>>>(ws, out);
    k3_softmax<<<N_ROWS, 256, 0, stream>>>(z, embed, ws, out);
    k4a_stats<<<1, 1024, 0, stream>>>(cluster_size, ws, out);
    k4b_embed<<<K_CODES, 256, 0, stream>>>(embed_avg, ws, out);
}